// Round 4
// baseline (321.037 us; speedup 1.0000x reference)
//
#include <hip/hip_runtime.h>
#include <hip/hip_bf16.h>
#include <hip/hip_fp16.h>
#include <math.h>

// ---------------------------------------------------------------------------
// DisplacementTensors: rad = MLP(radial_encode(|r|)) depends only on |r| ->
// tabulate [F(d) | F(d)@w_v | F(d)@w_d] interleaved (96 floats/row), 8192
// nearest-neighbor entries (3 MB, L2-resident).  CSR segment-sum: rank ->
// scan -> place packed 8B payload (f16 rs0,rs1,rs2 | u16 tab index) directly
// in CSR order -> one wave per node streams its slice, branch-free accumulate.
// dtype (bf16 vs f32) detected at runtime (flag in d_ws); this dataset is f32
// (WRITE_SIZE == 4B * out_size).
// ---------------------------------------------------------------------------

#define TSIZE 8192
#define DMAX  2.0f          // RBF centers <=1, width 1/8 -> F const beyond ~2
#define NPB   4             // waves (nodes) per block in k_nodes

__device__ __forceinline__ float lrelu(float x) { return x > 0.0f ? x : 0.1f * x; }

__device__ __forceinline__ float ldf(const void* p, int i, bool f32) {
    return f32 ? ((const float*)p)[i]
               : __bfloat162float(((const __hip_bfloat16*)p)[i]);
}
__device__ __forceinline__ void stf(void* p, size_t i, float v, bool f32) {
    if (f32) ((float*)p)[i] = v;
    else     ((__hip_bfloat16*)p)[i] = __float2bfloat16(v);
}

// --- fused: block 0 = dtype detection, blocks 1.. zero counts --------------
__global__ void k_prep(const void* r, int nbf16, int* flag,
                       int* __restrict__ counts, int N) {
    if (blockIdx.x == 0) {
        __shared__ int bad;
        if (threadIdx.x == 0) bad = 0;
        __syncthreads();
        const __hip_bfloat16* p = (const __hip_bfloat16*)r;
        int local = 0;
        for (int i = threadIdx.x; i < nbf16; i += blockDim.x) {
            float v = __bfloat162float(p[i]);
            if (!isfinite(v) || fabsf(v) > 1e5f) local = 1;
        }
        if (local) atomicOr(&bad, 1);
        __syncthreads();
        if (threadIdx.x == 0) flag[0] = bad;
    } else {
        int i = (blockIdx.x - 1) * blockDim.x + threadIdx.x;
        if (i < N) counts[i] = 0;
    }
}

// --- LUT build: weights staged in LDS, 8 entries per 64-thread block -------
#define O_WRAD 0
#define O_BRAD 256
#define O_WDIR 288
#define O_W1   1312
#define O_B1   3360
#define O_W2   3424
#define O_B2   7520
#define O_W3   7584
#define O_B3   9632
#define O_WV   9664
#define O_WD   10688
#define W_TOT  11712

__device__ __forceinline__ void load_seg(float* dst, const void* src, int cnt,
                                         bool f32, int tid) {
    for (int i = tid; i < cnt; i += 64) dst[i] = ldf(src, i, f32);
}

__global__ void __launch_bounds__(64) k_table(
        const void* __restrict__ w_rad, const void* __restrict__ b_rad,
        const void* __restrict__ w_direct,
        const void* __restrict__ w1, const void* __restrict__ b1,
        const void* __restrict__ w2, const void* __restrict__ b2,
        const void* __restrict__ w3, const void* __restrict__ b3,
        const void* __restrict__ w_v, const void* __restrict__ w_d,
        const int* __restrict__ flag,
        float* __restrict__ tabI) {
    __shared__ float W[W_TOT];
    __shared__ float Lh[32], Lt1[64], Lt2[64], Lrad[32];

    const bool f32 = flag[0] != 0;
    const int j = threadIdx.x;

    load_seg(W + O_WRAD, w_rad,    256,  f32, j);
    load_seg(W + O_BRAD, b_rad,    32,   f32, j);
    load_seg(W + O_WDIR, w_direct, 1024, f32, j);
    load_seg(W + O_W1,   w1,       2048, f32, j);
    load_seg(W + O_B1,   b1,       64,   f32, j);
    load_seg(W + O_W2,   w2,       4096, f32, j);
    load_seg(W + O_B2,   b2,       64,   f32, j);
    load_seg(W + O_W3,   w3,       2048, f32, j);
    load_seg(W + O_B3,   b3,       32,   f32, j);
    load_seg(W + O_WV,   w_v,      1024, f32, j);
    load_seg(W + O_WD,   w_d,      1024, f32, j);
    __syncthreads();

    const int per = 8;                       // entries per block
    const int base = blockIdx.x * per;

    for (int e = base; e < base + per; e++) {
        const float d = (float)e * (DMAX / (float)(TSIZE - 1));
        float enc[8];
#pragma unroll
        for (int k = 0; k < 8; k++) {
            float t = (d - (float)k * (1.0f / 7.0f)) * 8.0f;
            enc[k] = expf(-t * t);
        }

        if (j < 32) {
            float s = W[O_BRAD + j];
#pragma unroll
            for (int k = 0; k < 8; k++) s += enc[k] * W[O_WRAD + k * 32 + j];
            Lh[j] = s;
        }
        __syncthreads();

        {   // t1 = lrelu(h @ w1 + b1) [64]
            float s = W[O_B1 + j];
            for (int i = 0; i < 32; i++) s += Lh[i] * W[O_W1 + i * 64 + j];
            Lt1[j] = lrelu(s);
        }
        __syncthreads();

        {   // t2 = lrelu(t1 @ w2 + b2) [64]
            float s = W[O_B2 + j];
            for (int i = 0; i < 64; i++) s += Lt1[i] * W[O_W2 + i * 64 + j];
            Lt2[j] = lrelu(s);
        }
        __syncthreads();

        if (j < 32) {   // rad = h @ w_direct + (t2 @ w3 + b3)
            float s = W[O_B3 + j];
            for (int i = 0; i < 64; i++) s += Lt2[i] * W[O_W3 + i * 32 + j];
            for (int i = 0; i < 32; i++) s += Lh[i] * W[O_WDIR + i * 32 + j];
            Lrad[j] = s;
            tabI[e * 96 + j] = s;
        }
        __syncthreads();

        if (j < 32) {   // folded output transforms
            float sv = 0.0f, sd = 0.0f;
            for (int i = 0; i < 32; i++) {
                float ri = Lrad[i];
                sv += ri * W[O_WV + i * 32 + j];
                sd += ri * W[O_WD + i * 32 + j];
            }
            tabI[e * 96 + 32 + j] = sv;
            tabI[e * 96 + 64 + j] = sd;
        }
        __syncthreads();
    }
}

// --- CSR construction ------------------------------------------------------
__global__ void k_rank(const int* __restrict__ src, int* __restrict__ counts,
                       int* __restrict__ rank, int E) {
    int e = blockIdx.x * blockDim.x + threadIdx.x;
    if (e < E) rank[e] = atomicAdd(&counts[src[e]], 1);
}

__global__ void k_scan(const int* __restrict__ counts, int* __restrict__ rowstart,
                       int N, int E) {
    __shared__ int part[1024];
    const int t = threadIdx.x;
    const int CH = (N + 1023) / 1024;
    const int lo = t * CH;
    const int hi = min(lo + CH, N);

    int s = 0;
    for (int i = lo; i < hi; i++) s += counts[i];
    part[t] = s;
    __syncthreads();

    for (int off = 1; off < 1024; off <<= 1) {
        int v = part[t];
        int w = (t >= off) ? part[t - off] : 0;
        __syncthreads();
        part[t] = v + w;
        __syncthreads();
    }

    int run = (t == 0) ? 0 : part[t - 1];
    for (int i = lo; i < hi; i++) {
        rowstart[i] = run;
        run += counts[i];
    }
    if (t == 0) rowstart[N] = E;
}

// place packed payload into CSR slot (fast path), or permutation (fallback)
__global__ void k_place(const int* __restrict__ src, const int* __restrict__ rank,
                        const int* __restrict__ rowstart,
                        const void* __restrict__ r_ij, const int* __restrict__ flag,
                        uint2* __restrict__ eps, int* __restrict__ perm, int E) {
    int e = blockIdx.x * blockDim.x + threadIdx.x;
    if (e >= E) return;
    const int pos = rowstart[src[e]] + rank[e];
    if (eps) {
        const bool f32 = flag[0] != 0;
        const float x = ldf(r_ij, 3 * e + 0, f32);
        const float y = ldf(r_ij, 3 * e + 1, f32);
        const float z = ldf(r_ij, 3 * e + 2, f32);
        const float d2 = x * x + y * y + z * z;
        const float inv = rsqrtf(1.0f + 49.0f * d2);     // tens_sigmoid(7*r)
        const float u = fminf(sqrtf(d2), DMAX) * ((float)(TSIZE - 1) / DMAX);
        const unsigned int ti = (unsigned int)(u + 0.5f); // nearest, <= TSIZE-1
        const unsigned int h0 = __half_as_ushort(__float2half(7.0f * x * inv));
        const unsigned int h1 = __half_as_ushort(__float2half(7.0f * y * inv));
        const unsigned int h2 = __half_as_ushort(__float2half(7.0f * z * inv));
        eps[pos] = make_uint2(h0 | (h1 << 16), h2 | (ti << 16));
    } else {
        perm[pos] = e;
    }
}

// --- per-node accumulation: one wave per node, branch-free -----------------
// lane = (a = lane&31) x (half = lane>>5).
// b1 = (half? rd : rv) * (half? rs1 : 1);  b2 = rd * (half? rs2 : rs0);
// half0: A+=ra, V+=rv*rs, D[0][*]+=rd*rs0*rs;  half1: D[1][*],D[2][*].
__global__ void __launch_bounds__(64 * NPB) k_nodes(
    const uint2* __restrict__ eps,
    const int* __restrict__ perm,
    const void* __restrict__ r_ij,
    const int* __restrict__ rowstart,
    const float* __restrict__ tabI,
    const int* __restrict__ flag,
    void* __restrict__ out, int N) {
    const int wave = threadIdx.x >> 6;
    const int lane = threadIdx.x & 63;
    const int n = blockIdx.x * NPB + wave;
    if (n >= N) return;
    const int a = lane & 31;
    const bool hi = (lane >> 5) != 0;
    const bool f32 = flag[0] != 0;

    const int s0 = rowstart[n];
    const int s1 = rowstart[n + 1];

    float accR = 0.f, acc1 = 0.f, acc2 = 0.f, acc3 = 0.f,
          acc4 = 0.f, acc5 = 0.f, acc6 = 0.f;

    if (eps) {
        int idx = s0;
        for (; idx + 1 < s1; idx += 2) {          // unroll x2: overlap loads
            const uint2 qa = eps[idx];
            const uint2 qb = eps[idx + 1];
            const float ax = __half2float(__ushort_as_half((unsigned short)(qa.x & 0xffff)));
            const float ay = __half2float(__ushort_as_half((unsigned short)(qa.x >> 16)));
            const float az = __half2float(__ushort_as_half((unsigned short)(qa.y & 0xffff)));
            const int   ab = (int)(qa.y >> 16) * 96 + a;
            const float bx = __half2float(__ushort_as_half((unsigned short)(qb.x & 0xffff)));
            const float by = __half2float(__ushort_as_half((unsigned short)(qb.x >> 16)));
            const float bz = __half2float(__ushort_as_half((unsigned short)(qb.y & 0xffff)));
            const int   bb = (int)(qb.y >> 16) * 96 + a;

            const float raA = tabI[ab], rvA = tabI[ab + 32], rdA = tabI[ab + 64];
            const float raB = tabI[bb], rvB = tabI[bb + 32], rdB = tabI[bb + 64];

            const float b1A = (hi ? rdA : rvA) * (hi ? ay : 1.0f);
            const float b2A = rdA * (hi ? az : ax);
            const float b1B = (hi ? rdB : rvB) * (hi ? by : 1.0f);
            const float b2B = rdB * (hi ? bz : bx);

            accR += raA + raB;
            acc1 += b1A * ax + b1B * bx;
            acc2 += b1A * ay + b1B * by;
            acc3 += b1A * az + b1B * bz;
            acc4 += b2A * ax + b2B * bx;
            acc5 += b2A * ay + b2B * by;
            acc6 += b2A * az + b2B * bz;
        }
        if (idx < s1) {
            const uint2 q = eps[idx];
            const float x = __half2float(__ushort_as_half((unsigned short)(q.x & 0xffff)));
            const float y = __half2float(__ushort_as_half((unsigned short)(q.x >> 16)));
            const float z = __half2float(__ushort_as_half((unsigned short)(q.y & 0xffff)));
            const int   b = (int)(q.y >> 16) * 96 + a;
            const float ra = tabI[b], rv = tabI[b + 32], rd = tabI[b + 64];
            const float b1 = (hi ? rd : rv) * (hi ? y : 1.0f);
            const float b2 = rd * (hi ? z : x);
            accR += ra;
            acc1 += b1 * x; acc2 += b1 * y; acc3 += b1 * z;
            acc4 += b2 * x; acc5 += b2 * y; acc6 += b2 * z;
        }
    } else {
        for (int idx = s0; idx < s1; idx++) {
            const int e = perm[idx];
            const float x0 = ldf(r_ij, 3 * e + 0, f32);
            const float y0 = ldf(r_ij, 3 * e + 1, f32);
            const float z0 = ldf(r_ij, 3 * e + 2, f32);
            const float d2 = x0 * x0 + y0 * y0 + z0 * z0;
            const float inv = rsqrtf(1.0f + 49.0f * d2);
            const float x = 7.0f * x0 * inv, y = 7.0f * y0 * inv, z = 7.0f * z0 * inv;
            const float u = fminf(sqrtf(d2), DMAX) * ((float)(TSIZE - 1) / DMAX);
            const int b = (int)(u + 0.5f) * 96 + a;
            const float ra = tabI[b], rv = tabI[b + 32], rd = tabI[b + 64];
            const float b1 = (hi ? rd : rv) * (hi ? y : 1.0f);
            const float b2 = rd * (hi ? z : x);
            accR += ra;
            acc1 += b1 * x; acc2 += b1 * y; acc3 += b1 * z;
            acc4 += b2 * x; acc5 += b2 * y; acc6 += b2 * z;
        }
    }

    const size_t baseV = (size_t)N * 32;
    const size_t baseD = (size_t)N * 128;
    if (!hi) {
        stf(out, (size_t)n * 32 + a, accR, f32);
        const size_t vb = baseV + (size_t)n * 96 + a * 3;
        stf(out, vb + 0, acc1, f32);
        stf(out, vb + 1, acc2, f32);
        stf(out, vb + 2, acc3, f32);
        const size_t db = baseD + (size_t)n * 288 + a * 9;
        stf(out, db + 0, acc4, f32);
        stf(out, db + 1, acc5, f32);
        stf(out, db + 2, acc6, f32);
    } else {
        const size_t db = baseD + (size_t)n * 288 + a * 9;
        stf(out, db + 3, acc1, f32);
        stf(out, db + 4, acc2, f32);
        stf(out, db + 5, acc3, f32);
        stf(out, db + 6, acc4, f32);
        stf(out, db + 7, acc5, f32);
        stf(out, db + 8, acc6, f32);
    }
}

extern "C" void kernel_launch(void* const* d_in, const int* in_sizes, int n_in,
                              void* d_out, int out_size, void* d_ws, size_t ws_size,
                              hipStream_t stream) {
    const void* r_ij     = d_in[0];
    const void* w_rad    = d_in[1];
    const void* b_rad    = d_in[2];
    const void* w_direct = d_in[3];
    const void* w1       = d_in[4];
    const void* b1       = d_in[5];
    const void* w2       = d_in[6];
    const void* b2       = d_in[7];
    const void* w3       = d_in[8];
    const void* b3       = d_in[9];
    const void* w_v      = d_in[10];
    const void* w_d      = d_in[11];
    const int* edges_src = (const int*)d_in[12];

    const int E = in_sizes[12];
    const int N = out_size / 416;   // 32 + 96 + 288 per node

    const size_t epsBytes = (size_t)E * 8;
    const size_t tabBytes = (size_t)TSIZE * 96 * 4;
    const size_t intBytes = (size_t)(4 + N + (N + 1) + E + E) * 4;
    const bool use_eps = ws_size >= epsBytes + tabBytes + intBytes + 64;

    char* w = (char*)d_ws;
    uint2* eps    = use_eps ? (uint2*)w : nullptr;
    float* tabI   = (float*)(w + (use_eps ? epsBytes : 0));
    int* flag     = (int*)(tabI + TSIZE * 96);
    int* counts   = flag + 4;
    int* rowstart = counts + N;           // N+1
    int* rank     = rowstart + N + 1;     // E
    int* perm     = rank + E;             // E (fallback only)

    int nprobe = in_sizes[0] < 8192 ? in_sizes[0] : 8192;
    k_prep<<<1 + (N + 255) / 256, 256, 0, stream>>>(r_ij, nprobe, flag, counts, N);
    k_table<<<TSIZE / 8, 64, 0, stream>>>(w_rad, b_rad, w_direct, w1, b1, w2, b2,
                                          w3, b3, w_v, w_d, flag, tabI);
    k_rank<<<(E + 255) / 256, 256, 0, stream>>>(edges_src, counts, rank, E);
    k_scan<<<1, 1024, 0, stream>>>(counts, rowstart, N, E);
    k_place<<<(E + 255) / 256, 256, 0, stream>>>(edges_src, rank, rowstart,
                                                 r_ij, flag, eps, perm, E);
    k_nodes<<<(N + NPB - 1) / NPB, 64 * NPB, 0, stream>>>(
        eps, perm, r_ij, rowstart, tabI, flag, d_out, N);
}